// Round 5
// baseline (555.367 us; speedup 1.0000x reference)
//
#include <hip/hip_runtime.h>
#include <math.h>

#define BATCH 1024
#define TT    128
#define NBI   13
#define HH    128
#define T_INP 64
#define NG    512
#define NTHR  1024

typedef _Float16 half2v __attribute__((ext_vector_type(2)));

#if __has_builtin(__builtin_amdgcn_fdot2)
#define HAS_FDOT2 1
#else
#define HAS_FDOT2 0
#endif

__device__ __forceinline__ float dot2acc(float w, float h, float acc) {
#if HAS_FDOT2
    return __builtin_amdgcn_fdot2(__builtin_bit_cast(half2v, w),
                                  __builtin_bit_cast(half2v, h), acc, false);
#else
    half2v a = __builtin_bit_cast(half2v, w);
    half2v b = __builtin_bit_cast(half2v, h);
    return acc + (float)a[0] * (float)b[0] + (float)a[1] * (float)b[1];
#endif
}

__device__ __forceinline__ unsigned short f16b(float v) {
    return __builtin_bit_cast(unsigned short, (_Float16)v);
}
__device__ __forceinline__ float sigmoid_(float v) {
    return 1.0f / (1.0f + __expf(-v));
}
__device__ __forceinline__ float tanh_(float v) {
    float e = __expf(2.0f * v);
    return 1.0f - 2.0f / (e + 1.0f);
}

// ---- ws layout (bytes) ----
#define WS_WHH   0            // ushort[512*128] teacher W_hh (f16)
#define WS_WHAT  131072       // ushort[512*128] folded Ŵ = W_hh + W_ih@W_out (f16)
#define WS_WIH   262144       // ushort[512*16]  W_ih padded 13->16 (f16)
#define WS_WOUT  278528       // ushort[13*128]  W_out (f16)
#define WS_BT    282624       // float[512] teacher bias = b_ih+b_hh
#define WS_BA    284672       // float[512] auto bias = b_ih+b_hh + W_ih@b_out

__global__ void fold_kernel(const float* __restrict__ W_ih,
                            const float* __restrict__ W_hh,
                            const float* __restrict__ b_ih,
                            const float* __restrict__ b_hh,
                            const float* __restrict__ W_out,
                            const float* __restrict__ b_out,
                            unsigned char* __restrict__ ws)
{
    const int j = blockIdx.x;   // gate row 0..511
    const int k = threadIdx.x;  // hidden col 0..127
    unsigned short* whh16  = (unsigned short*)(ws + WS_WHH);
    unsigned short* what16 = (unsigned short*)(ws + WS_WHAT);
    unsigned short* wih16  = (unsigned short*)(ws + WS_WIH);
    unsigned short* wout16 = (unsigned short*)(ws + WS_WOUT);
    float* bias_t = (float*)(ws + WS_BT);
    float* bias_a = (float*)(ws + WS_BA);

    float whh = W_hh[j * HH + k];
    float acc = whh;
#pragma unroll
    for (int m = 0; m < NBI; ++m)
        acc += W_ih[j * NBI + m] * W_out[m * HH + k];
    whh16[j * HH + k]  = f16b(whh);
    what16[j * HH + k] = f16b(acc);

    if (k < 16) wih16[j * 16 + k] = (k < NBI) ? f16b(W_ih[j * NBI + k]) : 0;
    if (k == 0) {
        float bt = b_ih[j] + b_hh[j];
        bias_t[j] = bt;
        float ba = bt;
#pragma unroll
        for (int m = 0; m < NBI; ++m) ba += W_ih[j * NBI + m] * b_out[m];
        bias_a[j] = ba;
    }
    if (j < NBI) wout16[j * HH + k] = f16b(W_out[j * HH + k]);
}

// 1024 threads: lane pair (2r, 2r+1) owns gate row r; each holds HALF the
// W row (64 f16 = 32 VGPRs) -> total pressure ~55 regs fits the 64-reg/
// 8-wave-per-EU budget the allocator targets, so no spill/remat.
__global__ __launch_bounds__(NTHR, 4)
void lstm_main(const float* __restrict__ x,
               const float* __restrict__ b_out,
               const unsigned char* __restrict__ ws,
               float* __restrict__ out)
{
    const int tid  = threadIdx.x;
    const int b    = blockIdx.x;
    const int row  = tid >> 1;   // gate row 0..511
    const int half = tid & 1;    // K-half 0..1

    __shared__ __align__(16) unsigned short wih_s[NG * 16];    // 16 KB
    __shared__ __align__(16) unsigned short wout_s[NBI * HH];  // 3328 B
    __shared__ __align__(16) unsigned short h_s[HH];           // f16 hidden
    __shared__ __align__(16) unsigned short x_s[16];           // f16 input
    __shared__ float gate_s[NG];

    const unsigned short* whh16  = (const unsigned short*)(ws + WS_WHH);
    const unsigned short* what16 = (const unsigned short*)(ws + WS_WHAT);
    const float* bias_t = (const float*)(ws + WS_BT);
    const float* bias_a = (const float*)(ws + WS_BA);

    // stage small weights to LDS (shared by all rows)
    ((float4*)wih_s)[tid & 1023] = ((const float4*)(ws + WS_WIH))[tid & 1023];
    if (tid < 208) ((float4*)wout_s)[tid] = ((const float4*)(ws + WS_WOUT))[tid];

    // half-row of W_hh in registers: 8 float4 = 32 VGPRs
    float4 whf[8];
    {
        const float4* wp = (const float4*)(whh16 + row * HH + half * 64);
#pragma unroll
        for (int c2 = 0; c2 < 8; ++c2) whf[c2] = wp[c2];
    }
    float bias_cur = half ? 0.0f : bias_t[row];

    // projection role: waves 14-15 (tid 896..1023), 13 outputs x 8 partials
    const bool pw   = (tid >= 896);
    const int pidx  = tid - 896;                 // 0..127
    const int ppart = pidx & 7;
    const int pm    = (pw && pidx < 104) ? (pidx >> 3) : 0;  // clamped
    const bool pout = pw && (ppart == 0) && (pidx < 104);
    const float bo  = pout ? b_out[pm] : 0.0f;

    const float* xb = x   + (size_t)b * TT * NBI;
    float*       ob = out + (size_t)b * TT * NBI;

    float c = 0.0f;
    if (tid < HH) h_s[tid] = 0;
    if (tid >= 128 && tid < 144) {
        int k = tid - 128;
        float v = (k < NBI) ? xb[k] : 0.0f;
        x_s[k] = f16b(v);
        if (k < NBI) ob[k] = v;   // out[:,0,:] = x[:,0,:]
    }
    __syncthreads();

    // =========== teacher loop: t = 0..64, input = x[:,t] ===========
    for (int t = 0; t <= T_INP; ++t) {
        // G phase: partial dot over this thread's K-half
        float a0 = bias_cur, a1 = 0.f, a2 = 0.f, a3 = 0.f;
        const float4* h4 = ((const float4*)h_s) + half * 8;
#pragma unroll
        for (int cb = 0; cb < 8; ++cb) {
            float4 hv = h4[cb];
            a0 = dot2acc(whf[cb].x, hv.x, a0);
            a1 = dot2acc(whf[cb].y, hv.y, a1);
            a2 = dot2acc(whf[cb].z, hv.z, a2);
            a3 = dot2acc(whf[cb].w, hv.w, a3);
        }
        if (!half) {  // x contribution (half 0 only; W_ih from LDS)
            const float4* wi = (const float4*)(wih_s + row * 16);
            float4 wv0 = wi[0], wv1 = wi[1];
            const float4* x4 = (const float4*)x_s;
            float4 xv0 = x4[0], xv1 = x4[1];
            a0 = dot2acc(wv0.x, xv0.x, a0);
            a1 = dot2acc(wv0.y, xv0.y, a1);
            a2 = dot2acc(wv0.z, xv0.z, a2);
            a3 = dot2acc(wv0.w, xv0.w, a3);
            a0 = dot2acc(wv1.x, xv1.x, a0);
            a1 = dot2acc(wv1.y, xv1.y, a1);
            a2 = dot2acc(wv1.z, xv1.z, a2);
            a3 = dot2acc(wv1.w, xv1.w, a3);
        }
        float g = (a0 + a1) + (a2 + a3);
        g += __shfl_xor(g, 1, 64);     // combine the two K-halves
        if (!half) gate_s[row] = g;

        // lagged projection: out[t] = W_out h^(t) + b_out (t>=1)
        if (pw) {
            const float4* wo = (const float4*)(wout_s + pm * HH + ppart * 16);
            float4 w0 = wo[0], w1 = wo[1];
            const float4* hp = ((const float4*)h_s) + ppart * 2;
            float4 p0 = hp[0], p1 = hp[1];
            float ps = 0.0f;
            ps = dot2acc(w0.x, p0.x, ps);
            ps = dot2acc(w0.y, p0.y, ps);
            ps = dot2acc(w0.z, p0.z, ps);
            ps = dot2acc(w0.w, p0.w, ps);
            ps = dot2acc(w1.x, p1.x, ps);
            ps = dot2acc(w1.y, p1.y, ps);
            ps = dot2acc(w1.z, p1.z, ps);
            ps = dot2acc(w1.w, p1.w, ps);
            ps += __shfl_down(ps, 4, 64);
            ps += __shfl_down(ps, 2, 64);
            ps += __shfl_down(ps, 1, 64);
            if (pout && t >= 1) ob[t * NBI + pm] = ps + bo;
        }
        __syncthreads();  // B1: gates ready; h_s/x_s readers done

        // U phase: cell update + x prefetch
        if (tid < HH) {
            float ig = sigmoid_(gate_s[tid]);
            float fg = sigmoid_(gate_s[tid + 128]);
            float gg = tanh_(gate_s[tid + 256]);
            float og = sigmoid_(gate_s[tid + 384]);
            c = fg * c + ig * gg;
            h_s[tid] = f16b(og * tanh_(c));
        } else if (tid < 144 && t < T_INP) {
            int k = tid - 128;
            float v = (k < NBI) ? xb[(t + 1) * NBI + k] : 0.0f;
            x_s[k] = f16b(v);
        }
        __syncthreads();  // B2: h_s ready
    }

    // ---- switch to folded weights Ŵ = W_hh + W_ih@W_out, b̂ ----
    {
        const float4* ap = (const float4*)(what16 + row * HH + half * 64);
#pragma unroll
        for (int c2 = 0; c2 < 8; ++c2) whf[c2] = ap[c2];
        bias_cur = half ? 0.0f : bias_a[row];
    }

    // =========== auto loop: t = 65..126, gates = Ŵ·h + b̂ ===========
    for (int t = T_INP + 1; t < TT - 1; ++t) {
        float a0 = bias_cur, a1 = 0.f, a2 = 0.f, a3 = 0.f;
        const float4* h4 = ((const float4*)h_s) + half * 8;
#pragma unroll
        for (int cb = 0; cb < 8; ++cb) {
            float4 hv = h4[cb];
            a0 = dot2acc(whf[cb].x, hv.x, a0);
            a1 = dot2acc(whf[cb].y, hv.y, a1);
            a2 = dot2acc(whf[cb].z, hv.z, a2);
            a3 = dot2acc(whf[cb].w, hv.w, a3);
        }
        float g = (a0 + a1) + (a2 + a3);
        g += __shfl_xor(g, 1, 64);
        if (!half) gate_s[row] = g;

        if (pw) {
            const float4* wo = (const float4*)(wout_s + pm * HH + ppart * 16);
            float4 w0 = wo[0], w1 = wo[1];
            const float4* hp = ((const float4*)h_s) + ppart * 2;
            float4 p0 = hp[0], p1 = hp[1];
            float ps = 0.0f;
            ps = dot2acc(w0.x, p0.x, ps);
            ps = dot2acc(w0.y, p0.y, ps);
            ps = dot2acc(w0.z, p0.z, ps);
            ps = dot2acc(w0.w, p0.w, ps);
            ps = dot2acc(w1.x, p1.x, ps);
            ps = dot2acc(w1.y, p1.y, ps);
            ps = dot2acc(w1.z, p1.z, ps);
            ps = dot2acc(w1.w, p1.w, ps);
            ps += __shfl_down(ps, 4, 64);
            ps += __shfl_down(ps, 2, 64);
            ps += __shfl_down(ps, 1, 64);
            if (pout) ob[t * NBI + pm] = ps + bo;
        }
        __syncthreads();  // B1

        if (tid < HH) {
            float ig = sigmoid_(gate_s[tid]);
            float fg = sigmoid_(gate_s[tid + 128]);
            float gg = tanh_(gate_s[tid + 256]);
            float og = sigmoid_(gate_s[tid + 384]);
            c = fg * c + ig * gg;
            h_s[tid] = f16b(og * tanh_(c));
        }
        __syncthreads();  // B2
    }

    // ---- epilogue: out[127] = W_out h^(127) + b_out ----
    if (pw) {
        const float4* wo = (const float4*)(wout_s + pm * HH + ppart * 16);
        float4 w0 = wo[0], w1 = wo[1];
        const float4* hp = ((const float4*)h_s) + ppart * 2;
        float4 p0 = hp[0], p1 = hp[1];
        float ps = 0.0f;
        ps = dot2acc(w0.x, p0.x, ps);
        ps = dot2acc(w0.y, p0.y, ps);
        ps = dot2acc(w0.z, p0.z, ps);
        ps = dot2acc(w0.w, p0.w, ps);
        ps = dot2acc(w1.x, p1.x, ps);
        ps = dot2acc(w1.y, p1.y, ps);
        ps = dot2acc(w1.z, p1.z, ps);
        ps = dot2acc(w1.w, p1.w, ps);
        ps += __shfl_down(ps, 4, 64);
        ps += __shfl_down(ps, 2, 64);
        ps += __shfl_down(ps, 1, 64);
        if (pout) ob[(TT - 1) * NBI + pm] = ps + bo;
    }
}

extern "C" void kernel_launch(void* const* d_in, const int* in_sizes, int n_in,
                              void* d_out, int out_size, void* d_ws, size_t ws_size,
                              hipStream_t stream)
{
    const float* x     = (const float*)d_in[0];
    const float* W_ih  = (const float*)d_in[1];
    const float* W_hh  = (const float*)d_in[2];
    const float* b_ih  = (const float*)d_in[3];
    const float* b_hh  = (const float*)d_in[4];
    const float* W_out = (const float*)d_in[5];
    const float* b_out = (const float*)d_in[6];
    float* out = (float*)d_out;
    unsigned char* ws = (unsigned char*)d_ws;

    fold_kernel<<<NG, HH, 0, stream>>>(W_ih, W_hh, b_ih, b_hh, W_out, b_out, ws);
    lstm_main<<<BATCH, NTHR, 0, stream>>>(x, b_out, ws, out);
}

// Round 6
// 380.918 us; speedup vs baseline: 1.4580x; 1.4580x over previous
//
#include <hip/hip_runtime.h>
#include <math.h>

#define BATCH 1024
#define TT    128
#define NBI   13
#define HH    128
#define T_INP 64
#define NG    512

typedef _Float16 half2v __attribute__((ext_vector_type(2)));
typedef float f32x4 __attribute__((ext_vector_type(4)));

#if __has_builtin(__builtin_amdgcn_fdot2)
#define HAS_FDOT2 1
#else
#define HAS_FDOT2 0
#endif

__device__ __forceinline__ float dot2acc(float w, float h, float acc) {
#if HAS_FDOT2
    return __builtin_amdgcn_fdot2(__builtin_bit_cast(half2v, w),
                                  __builtin_bit_cast(half2v, h), acc, false);
#else
    half2v a = __builtin_bit_cast(half2v, w);
    half2v b = __builtin_bit_cast(half2v, h);
    return acc + (float)a[0] * (float)b[0] + (float)a[1] * (float)b[1];
#endif
}

__device__ __forceinline__ unsigned short f16b(float v) {
    return __builtin_bit_cast(unsigned short, (_Float16)v);
}
__device__ __forceinline__ float sigmoid_(float v) {
    return 1.0f / (1.0f + __expf(-v));
}
__device__ __forceinline__ float tanh_(float v) {
    float e = __expf(2.0f * v);
    return 1.0f - 2.0f / (e + 1.0f);
}

// Volatile-asm global load: the result of a volatile asm cannot be
// rematerialized or sunk into a loop, so the loaded weights MUST stay
// register-resident (spill would need scratch, which pressure<budget avoids).
__device__ __forceinline__ f32x4 gload4(const void* p) {
    f32x4 r;
    asm volatile("global_load_dwordx4 %0, %1, off"
                 : "=v"(r)
                 : "v"((unsigned long long)p)
                 : "memory");
    return r;
}
__device__ __forceinline__ void waitvm() {
    asm volatile("s_waitcnt vmcnt(0)" ::: "memory");
}

// ---- ws layout (bytes) ----
#define WS_WHH   0            // ushort[512*128] teacher W_hh (f16)
#define WS_WHAT  131072       // ushort[512*128] folded Ŵ = W_hh + W_ih@W_out (f16)
#define WS_WIH   262144       // ushort[512*16]  W_ih padded 13->16 (f16)
#define WS_WOUT  278528       // ushort[13*128]  W_out (f16)
#define WS_BT    282624       // float[512] teacher bias = b_ih+b_hh
#define WS_BA    284672       // float[512] auto bias = b_ih+b_hh + W_ih@b_out

__global__ void fold_kernel(const float* __restrict__ W_ih,
                            const float* __restrict__ W_hh,
                            const float* __restrict__ b_ih,
                            const float* __restrict__ b_hh,
                            const float* __restrict__ W_out,
                            const float* __restrict__ b_out,
                            unsigned char* __restrict__ ws)
{
    const int j = blockIdx.x;   // gate row 0..511
    const int k = threadIdx.x;  // hidden col 0..127
    unsigned short* whh16  = (unsigned short*)(ws + WS_WHH);
    unsigned short* what16 = (unsigned short*)(ws + WS_WHAT);
    unsigned short* wih16  = (unsigned short*)(ws + WS_WIH);
    unsigned short* wout16 = (unsigned short*)(ws + WS_WOUT);
    float* bias_t = (float*)(ws + WS_BT);
    float* bias_a = (float*)(ws + WS_BA);

    float whh = W_hh[j * HH + k];
    float acc = whh;
#pragma unroll
    for (int m = 0; m < NBI; ++m)
        acc += W_ih[j * NBI + m] * W_out[m * HH + k];
    whh16[j * HH + k]  = f16b(whh);
    what16[j * HH + k] = f16b(acc);

    if (k < 16) wih16[j * 16 + k] = (k < NBI) ? f16b(W_ih[j * NBI + k]) : 0;
    if (k == 0) {
        float bt = b_ih[j] + b_hh[j];
        bias_t[j] = bt;
        float ba = bt;
#pragma unroll
        for (int m = 0; m < NBI; ++m) ba += W_ih[j * NBI + m] * b_out[m];
        bias_a[j] = ba;
    }
    if (j < NBI) wout16[j * HH + k] = f16b(W_out[j * HH + k]);
}

__global__ void __launch_bounds__(512)
__attribute__((amdgpu_waves_per_eu(4, 4)))
lstm_main(const float* __restrict__ x,
          const float* __restrict__ b_out,
          const unsigned char* __restrict__ ws,
          float* __restrict__ out)
{
    const int b = blockIdx.x;
    const int j = threadIdx.x;

    const unsigned short* whh16  = (const unsigned short*)(ws + WS_WHH);
    const unsigned short* what16 = (const unsigned short*)(ws + WS_WHAT);
    const unsigned short* wih16  = (const unsigned short*)(ws + WS_WIH);
    const unsigned short* wout16 = (const unsigned short*)(ws + WS_WOUT);
    const float* bias_t = (const float*)(ws + WS_BT);
    const float* bias_a = (const float*)(ws + WS_BA);

    __shared__ __align__(16) unsigned short h_s[HH];  // f16 hidden state
    __shared__ __align__(16) unsigned short x_s[16];  // f16 input (padded)
    __shared__ float gate_s[NG];

    // ---- register-resident weights: 64 VGPRs of f16-packed W_hh row ----
    f32x4 whf[16];
    {
        const unsigned short* wrow = whh16 + j * HH;
#pragma unroll
        for (int c2 = 0; c2 < 16; ++c2) whf[c2] = gload4(wrow + c2 * 8);
    }
    f32x4 wif0 = gload4(wih16 + j * 16);
    f32x4 wif1 = gload4(wih16 + j * 16 + 8);

    // projection role: 13 outputs x 8 partials = 104 threads
    const int part = j & 7;
    const int m    = (j < 104) ? (j >> 3) : 0;   // clamped for uniform asm load
    f32x4 wof0 = gload4(wout16 + m * HH + part * 16);
    f32x4 wof1 = gload4(wout16 + m * HH + part * 16 + 8);
    waitvm();   // drain all volatile-asm loads before use

    float bias_cur = bias_t[j];
    float bo = 0.0f;
    if (part == 0 && j < 104) bo = b_out[m];

    const float* xb = x   + (size_t)b * TT * NBI;
    float*       ob = out + (size_t)b * TT * NBI;

    float c = 0.0f;
    if (j < HH) h_s[j] = 0;
    if (j < 16) {
        float v = (j < NBI) ? xb[j] : 0.0f;
        x_s[j] = f16b(v);
        if (j < NBI) ob[j] = v;   // out[:,0,:] = x[:,0,:]
    }
    __syncthreads();

    // =========== teacher loop: t = 0..64, input = x[:,t] ===========
    for (int t = 0; t <= T_INP; ++t) {
        float a0 = bias_cur, a1 = 0.f, a2 = 0.f, a3 = 0.f;
        const f32x4* h4 = (const f32x4*)h_s;
#pragma unroll
        for (int cb = 0; cb < 16; ++cb) {
            f32x4 hv = h4[cb];
            a0 = dot2acc(whf[cb].x, hv.x, a0);
            a1 = dot2acc(whf[cb].y, hv.y, a1);
            a2 = dot2acc(whf[cb].z, hv.z, a2);
            a3 = dot2acc(whf[cb].w, hv.w, a3);
        }
        {
            const f32x4* x4 = (const f32x4*)x_s;
            f32x4 xv0 = x4[0], xv1 = x4[1];
            a0 = dot2acc(wif0.x, xv0.x, a0);
            a1 = dot2acc(wif0.y, xv0.y, a1);
            a2 = dot2acc(wif0.z, xv0.z, a2);
            a3 = dot2acc(wif0.w, xv0.w, a3);
            a0 = dot2acc(wif1.x, xv1.x, a0);
            a1 = dot2acc(wif1.y, xv1.y, a1);
            a2 = dot2acc(wif1.z, xv1.z, a2);
            a3 = dot2acc(wif1.w, xv1.w, a3);
        }
        gate_s[j] = (a0 + a1) + (a2 + a3);

        // lagged projection: out[t] = W_out h^(t) + b_out (t>=1)
        float ps = 0.0f;
        if (t >= 1 && j < 104) {
            const f32x4* hp = ((const f32x4*)h_s) + part * 2;
            f32x4 p0 = hp[0], p1 = hp[1];
            ps = dot2acc(wof0.x, p0.x, ps);
            ps = dot2acc(wof0.y, p0.y, ps);
            ps = dot2acc(wof0.z, p0.z, ps);
            ps = dot2acc(wof0.w, p0.w, ps);
            ps = dot2acc(wof1.x, p1.x, ps);
            ps = dot2acc(wof1.y, p1.y, ps);
            ps = dot2acc(wof1.z, p1.z, ps);
            ps = dot2acc(wof1.w, p1.w, ps);
        }
        if (j < 128) {
            ps += __shfl_down(ps, 4, 64);
            ps += __shfl_down(ps, 2, 64);
            ps += __shfl_down(ps, 1, 64);
            if (t >= 1 && part == 0 && j < 104)
                ob[t * NBI + m] = ps + bo;
        }
        __syncthreads();  // gates ready; h_s/x_s readers done

        if (j < HH) {
            float ig = sigmoid_(gate_s[j]);
            float fg = sigmoid_(gate_s[j + 128]);
            float gg = tanh_(gate_s[j + 256]);
            float og = sigmoid_(gate_s[j + 384]);
            c = fg * c + ig * gg;
            h_s[j] = f16b(og * tanh_(c));
        } else if (j < 144) {
            if (t < T_INP) {
                int k = j - 128;
                float v = (k < NBI) ? xb[(t + 1) * NBI + k] : 0.0f;
                x_s[k] = f16b(v);
            }
        }
        __syncthreads();  // h_s ready for next step
    }

    // ---- switch to folded weights Ŵ = W_hh + W_ih@W_out, b̂ ----
    {
        const unsigned short* arow = what16 + j * HH;
#pragma unroll
        for (int c2 = 0; c2 < 16; ++c2) whf[c2] = gload4(arow + c2 * 8);
        waitvm();
        bias_cur = bias_a[j];
    }

    // =========== auto loop: t = 65..126, gates = Ŵ·h + b̂ ===========
    for (int t = T_INP + 1; t < TT - 1; ++t) {
        float a0 = bias_cur, a1 = 0.f, a2 = 0.f, a3 = 0.f;
        const f32x4* h4 = (const f32x4*)h_s;
#pragma unroll
        for (int cb = 0; cb < 16; ++cb) {
            f32x4 hv = h4[cb];
            a0 = dot2acc(whf[cb].x, hv.x, a0);
            a1 = dot2acc(whf[cb].y, hv.y, a1);
            a2 = dot2acc(whf[cb].z, hv.z, a2);
            a3 = dot2acc(whf[cb].w, hv.w, a3);
        }
        gate_s[j] = (a0 + a1) + (a2 + a3);

        // lagged projection: out[t] = W_out h^(t) + b_out
        float ps = 0.0f;
        if (j < 104) {
            const f32x4* hp = ((const f32x4*)h_s) + part * 2;
            f32x4 p0 = hp[0], p1 = hp[1];
            ps = dot2acc(wof0.x, p0.x, ps);
            ps = dot2acc(wof0.y, p0.y, ps);
            ps = dot2acc(wof0.z, p0.z, ps);
            ps = dot2acc(wof0.w, p0.w, ps);
            ps = dot2acc(wof1.x, p1.x, ps);
            ps = dot2acc(wof1.y, p1.y, ps);
            ps = dot2acc(wof1.z, p1.z, ps);
            ps = dot2acc(wof1.w, p1.w, ps);
        }
        if (j < 128) {
            ps += __shfl_down(ps, 4, 64);
            ps += __shfl_down(ps, 2, 64);
            ps += __shfl_down(ps, 1, 64);
            if (part == 0 && j < 104)
                ob[t * NBI + m] = ps + bo;
        }
        __syncthreads();

        if (j < HH) {
            float ig = sigmoid_(gate_s[j]);
            float fg = sigmoid_(gate_s[j + 128]);
            float gg = tanh_(gate_s[j + 256]);
            float og = sigmoid_(gate_s[j + 384]);
            c = fg * c + ig * gg;
            h_s[j] = f16b(og * tanh_(c));
        }
        __syncthreads();
    }

    // ---- epilogue: out[127] = W_out h^(127) + b_out ----
    {
        float ps = 0.0f;
        if (j < 104) {
            const f32x4* hp = ((const f32x4*)h_s) + part * 2;
            f32x4 p0 = hp[0], p1 = hp[1];
            ps = dot2acc(wof0.x, p0.x, ps);
            ps = dot2acc(wof0.y, p0.y, ps);
            ps = dot2acc(wof0.z, p0.z, ps);
            ps = dot2acc(wof0.w, p0.w, ps);
            ps = dot2acc(wof1.x, p1.x, ps);
            ps = dot2acc(wof1.y, p1.y, ps);
            ps = dot2acc(wof1.z, p1.z, ps);
            ps = dot2acc(wof1.w, p1.w, ps);
        }
        if (j < 128) {
            ps += __shfl_down(ps, 4, 64);
            ps += __shfl_down(ps, 2, 64);
            ps += __shfl_down(ps, 1, 64);
            if (part == 0 && j < 104)
                ob[(TT - 1) * NBI + m] = ps + bo;
        }
    }
}

extern "C" void kernel_launch(void* const* d_in, const int* in_sizes, int n_in,
                              void* d_out, int out_size, void* d_ws, size_t ws_size,
                              hipStream_t stream)
{
    const float* x     = (const float*)d_in[0];
    const float* W_ih  = (const float*)d_in[1];
    const float* W_hh  = (const float*)d_in[2];
    const float* b_ih  = (const float*)d_in[3];
    const float* b_hh  = (const float*)d_in[4];
    const float* W_out = (const float*)d_in[5];
    const float* b_out = (const float*)d_in[6];
    float* out = (float*)d_out;
    unsigned char* ws = (unsigned char*)d_ws;

    fold_kernel<<<NG, HH, 0, stream>>>(W_ih, W_hh, b_ih, b_hh, W_out, b_out, ws);
    lstm_main<<<BATCH, 512, 0, stream>>>(x, b_out, ws, out);
}